// Round 1
// 317.547 us; speedup vs baseline: 1.0012x; 1.0012x over previous
//
#include <hip/hip_runtime.h>
#include <cstdint>
#include <math.h>

#define NB 64
#define NP 8732
#define NC 81
#define NG 16
#define THRESH 0.5f
#define NBP (NB * NP)
#define MT 512           // match_mine block size (8 waves)
#define NSW 18           // ceil(NP / MT)

// ---------------------------------------------------------------------------
// Kernel 1: log-sum-exp per row (independent of matching). Also zeroes the
// 64-byte accumulator block (block 0) so no separate memset dispatch is
// needed — match_mine launches after lse completes (stream order).
// ---------------------------------------------------------------------------
__global__ __launch_bounds__(256) void lse_kernel(
    const float* __restrict__ scores,   // [B*P, C]
    float2* __restrict__ lse_s0,        // [B*P] {lse, score0}
    unsigned long long* __restrict__ zero64)  // ws base: acc/total_pos/done
{
    if (blockIdx.x == 0 && threadIdx.x < 8)
        zero64[threadIdx.x] = 0ull;     // zeroes acc[0..2], total_pos, done

    __shared__ __align__(16) float tile[64 * NC];  // 20736 B
    const int t = threadIdx.x;
    const size_t row0 = (size_t)blockIdx.x * 64;
    const float* gbase = scores + row0 * NC;

    const float4* g4 = (const float4*)gbase;
    float4* l4 = (float4*)tile;
#pragma unroll
    for (int i = 0; i < 5; ++i)
        l4[i * 256 + t] = g4[i * 256 + t];
    if (t < 64) tile[5120 + t] = gbase[5120 + t];
    __syncthreads();

    const int r = t >> 2;
    const int c4 = t & 3;
    const float* rp = tile + r * NC;
    float s = 0.0f;
#pragma unroll
    for (int i = 0; i < 21; ++i) {
        const int j = c4 + 4 * i;
        if (j < NC) s += __expf(rp[j]);
    }
    s += __shfl_xor(s, 1, 64);
    s += __shfl_xor(s, 2, 64);

    if (c4 == 0)
        lse_s0[row0 + r] = make_float2(__logf(s), rp[0]);
}

// ---------------------------------------------------------------------------
// Kernel 2: fused match + CE assembly + hard-negative select. One 512-thread
// block per image. gt data lives in VGPRs during the IoU phase.
// NOTE: __launch_bounds__(MT) not (MT,2): with only 64 blocks on 256 CUs at
// most 1 block/CU is resident, so the 128-VGPR cap from min-waves=2 bought
// nothing and forced scratch spills of the ~180-VGPR phase-A live set
// (rgt 64 + rga 16 + bp 32 + ls 36 + temps). 256-VGPR budget -> no spills.
// Top-k select: monotone key = ce*2048 (16-bit), 2 radix passes, digit picked
// by a single-wave shfl suffix-scan. Finalize fused in via done-counter.
// ---------------------------------------------------------------------------
__global__ __launch_bounds__(MT) void match_mine_kernel(
    const float* __restrict__ gt_boxes,    // [B,G,4] corner form
    const int* __restrict__ gt_labels,     // [B,G]
    const float* __restrict__ priors,      // [P,4] center form
    const float* __restrict__ pred_boxes,  // [B,P,4]
    const float* __restrict__ scores,      // [B,P,C]
    const float2* __restrict__ lse_s0,     // [B*P]
    double* __restrict__ acc,              // [0]=l1, [1]=pos, [2]=neg
    int* __restrict__ total_pos,
    int* __restrict__ done,
    float* __restrict__ out)
{
    __shared__ float s_ce[NP];             // overlaps, then ce values
    __shared__ unsigned char s_idx[NP];    // best gt per prior
    __shared__ __align__(16) float s_gt[NG][4];
    __shared__ int   s_lab[NG];
    __shared__ float w_val[8][NG];
    __shared__ int   w_idx[8][NG];
    __shared__ int   s_bp[NG];
    __shared__ float w_l1[8], w_pos[8], w_ns[8];
    __shared__ int   w_np[8];
    __shared__ __align__(16) int hist[256];
    __shared__ int   s_digit, s_rem, s_k;

    const int b = blockIdx.x;
    const int tid = threadIdx.x;
    const int lane = tid & 63;
    const int wid = tid >> 6;

    if (tid < NG * 4) ((float*)s_gt)[tid] = gt_boxes[b * NG * 4 + tid];
    if (tid >= 64 && tid < 64 + NG) s_lab[tid - 64] = gt_labels[b * NG + (tid - 64)];
    __syncthreads();

    // Prefetch lse_s0 into registers; consumed in phase B (hidden under A).
    float2 ls[NSW];
#pragma unroll
    for (int i = 0; i < NSW; ++i) {
        const int p = tid + i * MT;
        ls[i] = (p < NP) ? lse_s0[(size_t)b * NP + p] : make_float2(0.0f, 0.0f);
    }

    // Hoist gt boxes + areas into registers.
    float4 rgt[NG];
    float  rga[NG];
#pragma unroll
    for (int g = 0; g < NG; ++g) {
        rgt[g] = ((const float4*)s_gt)[g];
        rga[g] = (rgt[g].z - rgt[g].x) * (rgt[g].w - rgt[g].y);
    }

    // ---- Phase A: IoU; per-prior argmax over gt; per-gt argmax over priors.
    float bp_val[NG];
    int   bp_pidx[NG];
#pragma unroll
    for (int g = 0; g < NG; ++g) { bp_val[g] = -1.0f; bp_pidx[g] = 0; }

    for (int p = tid; p < NP; p += MT) {
        const float4 pr = ((const float4*)priors)[p];
        const float px1 = pr.x - pr.z * 0.5f;
        const float py1 = pr.y - pr.w * 0.5f;
        const float px2 = pr.x + pr.z * 0.5f;
        const float py2 = pr.y + pr.w * 0.5f;
        const float ap = (px2 - px1) * (py2 - py1);
        float bt_ov = -1.0f;
        int   bt_idx = 0;
#pragma unroll
        for (int g = 0; g < NG; ++g) {
            const float ltx = fmaxf(rgt[g].x, px1);
            const float lty = fmaxf(rgt[g].y, py1);
            const float rbx = fminf(rgt[g].z, px2);
            const float rby = fminf(rgt[g].w, py2);
            const float wx = fmaxf(rbx - ltx, 0.0f);
            const float wy = fmaxf(rby - lty, 0.0f);
            const float inter = wx * wy;
            const float iou = __fdividef(inter, rga[g] + ap - inter);
            if (iou > bt_ov) { bt_ov = iou; bt_idx = g; }             // first max over g
            if (iou > bp_val[g]) { bp_val[g] = iou; bp_pidx[g] = p; } // first max over p
        }
        s_ce[p] = bt_ov;
        s_idx[p] = (unsigned char)bt_idx;
    }

    // Per-wave shuffle argmax (val desc, idx asc on ties) per gt.
#pragma unroll
    for (int g = 0; g < NG; ++g) {
        float v = bp_val[g];
        int   ix = bp_pidx[g];
#pragma unroll
        for (int off = 32; off > 0; off >>= 1) {
            const float v2 = __shfl_xor(v, off, 64);
            const int   i2 = __shfl_xor(ix, off, 64);
            if (v2 > v || (v2 == v && i2 < ix)) { v = v2; ix = i2; }
        }
        if (lane == 0) { w_val[wid][g] = v; w_idx[wid][g] = ix; }
    }
    __syncthreads();
    if (tid < NG) {
        float bv = w_val[0][tid];
        int   bi = w_idx[0][tid];
#pragma unroll
        for (int w = 1; w < 8; ++w) {
            const float v2 = w_val[w][tid];
            const int   i2 = w_idx[w][tid];
            if (v2 > bv || (v2 == bv && i2 < bi)) { bv = v2; bi = i2; }
        }
        s_bp[tid] = bi;
    }
    __syncthreads();
    if (tid == 0) {   // sequential override: later g wins on duplicate priors
        for (int g = 0; g < NG; ++g) {
            const int p = s_bp[g];
            s_ce[p] = 2.0f;
            s_idx[p] = (unsigned char)g;
        }
    }
    __syncthreads();

    // ---- Phase B: confidence targets, CE assembly, L1 on positives.
    int my_npos = 0;
    float my_l1 = 0.0f, my_pos = 0.0f;
#pragma unroll
    for (int i = 0; i < NSW; ++i) {
        const int p = tid + i * MT;
        if (p < NP) {
            const int g = s_idx[p];
            const float ov = s_ce[p];
            const int cf = (ov < THRESH) ? 0 : s_lab[g];
            if (cf != 0) {
                my_pos += ls[i].x - scores[((size_t)b * NP + p) * NC + cf];
                ++my_npos;
                s_ce[p] = 0.0f;
                const float4 pr = ((const float4*)priors)[p];
                const float x1 = s_gt[g][0], y1 = s_gt[g][1];
                const float x2 = s_gt[g][2], y2 = s_gt[g][3];
                const float mcx = (x1 + x2) * 0.5f;
                const float mcy = (y1 + y2) * 0.5f;
                const float mw = x2 - x1, mh = y2 - y1;
                const float gx = (mcx - pr.x) / (0.1f * pr.z);
                const float gy = (mcy - pr.y) / (0.1f * pr.w);
                const float gw = logf(mw / pr.z) / 0.2f;
                const float gh = logf(mh / pr.w) / 0.2f;
                const float4 pb = ((const float4*)pred_boxes)[(size_t)b * NP + p];
                my_l1 += fabsf(pb.x - gx) + fabsf(pb.y - gy) +
                         fabsf(pb.z - gw) + fabsf(pb.w - gh);
            } else {
                s_ce[p] = ls[i].x - ls[i].y;   // lse - score0 >= 0
            }
        }
    }

#pragma unroll
    for (int off = 32; off > 0; off >>= 1) {
        my_l1 += __shfl_xor(my_l1, off, 64);
        my_pos += __shfl_xor(my_pos, off, 64);
        my_npos += __shfl_xor(my_npos, off, 64);
    }
    if (lane == 0) { w_l1[wid] = my_l1; w_pos[wid] = my_pos; w_np[wid] = my_npos; }
    __syncthreads();
    if (tid == 0) {
        int np = 0;
#pragma unroll
        for (int w = 0; w < 8; ++w) np += w_np[w];
        s_k = np;
    }
    __syncthreads();

    // ---- Phase C: top-k sum via 2-pass radix select on key = ce * 2048.
    int k = 3 * s_k;
    if (k > NP) k = NP;
    double neg_total = 0.0;
    if (k > 0) {   // block-uniform branch
        int rem = k;
        unsigned int d1 = 0;
#pragma unroll
        for (int pass = 0; pass < 2; ++pass) {
            if (tid < 256) hist[tid] = 0;
            __syncthreads();
            for (int p = tid; p < NP; p += MT) {
                const unsigned int key = (unsigned int)(s_ce[p] * 2048.0f);
                if (pass == 0)
                    atomicAdd(&hist[key >> 8], 1);
                else if ((key >> 8) == d1)
                    atomicAdd(&hist[key & 255u], 1);
            }
            __syncthreads();
            if (wid == 0) {
                // Single-wave digit pick: b128 read + shfl suffix-scan.
                const int4 h = ((const int4*)hist)[lane];  // bins 4*lane..4*lane+3
                const int local = h.x + h.y + h.z + h.w;
                int suf = local;
#pragma unroll
                for (int off = 1; off < 64; off <<= 1) {
                    const int o = __shfl_down(suf, off, 64);
                    if (lane + off < 64) suf += o;
                }
                const int above = suf - local;   // count in lanes > lane
                const int ge3 = above + h.w;     // count with digit >= 4l+3
                const int ge2 = ge3 + h.z;
                const int ge1 = ge2 + h.y;
                const int ge0 = ge1 + h.x;
                const unsigned long long mask = __ballot(ge0 >= rem);
                if (mask == 0) {                 // defensive; invariant: rem<=total
                    if (lane == 0) { s_digit = 0; s_rem = rem; }
                } else {
                    const int lstar = 63 - __clzll(mask);
                    if (lane == lstar) {
                        int d, greater;
                        if (ge3 >= rem)      { d = 4 * lane + 3; greater = above; }
                        else if (ge2 >= rem) { d = 4 * lane + 2; greater = ge3; }
                        else if (ge1 >= rem) { d = 4 * lane + 1; greater = ge2; }
                        else                 { d = 4 * lane + 0; greater = ge1; }
                        s_digit = d;
                        s_rem = rem - greater;
                    }
                }
            }
            __syncthreads();
            if (pass == 0) d1 = (unsigned int)s_digit;
            rem = s_rem;
            __syncthreads();
        }

        const unsigned int T = (d1 << 8) | (unsigned int)s_digit;
        float local = 0.0f;
        for (int p = tid; p < NP; p += MT) {
            const float x = s_ce[p];
            if ((unsigned int)(x * 2048.0f) > T) local += x;
        }
#pragma unroll
        for (int off = 32; off > 0; off >>= 1)
            local += __shfl_xor(local, off, 64);
        if (lane == 0) w_ns[wid] = local;
        __syncthreads();
        if (tid == 0) {
            float ns = 0.0f;
#pragma unroll
            for (int w = 0; w < 8; ++w) ns += w_ns[w];
            neg_total = (double)ns +
                        (double)rem * (((double)T + 0.5) * (1.0 / 2048.0));
        }
    }

    if (tid == 0) {
        float l1 = 0.0f, ps = 0.0f;
#pragma unroll
        for (int w = 0; w < 8; ++w) { l1 += w_l1[w]; ps += w_pos[w]; }
        atomicAdd(&acc[0], (double)l1);
        atomicAdd(&acc[1], (double)ps);
        atomicAdd(&acc[2], neg_total);
        atomicAdd(total_pos, s_k);
        __threadfence();
        if (atomicAdd(done, 1) == NB - 1) {
            // Last block finalizes; atomic reads are device-scope coherent.
            __threadfence();
            const double tp  = (double)atomicAdd(total_pos, 0);
            const double dl1 = atomicAdd(&acc[0], 0.0);
            const double dps = atomicAdd(&acc[1], 0.0);
            const double dng = atomicAdd(&acc[2], 0.0);
            out[0] = (float)((dng + dps) / tp);   // confidence loss
            out[1] = (float)(dl1 / (tp * 4.0));   // ALPHA * location loss
        }
    }
}

// ---------------------------------------------------------------------------
extern "C" void kernel_launch(void* const* d_in, const int* in_sizes, int n_in,
                              void* d_out, int out_size, void* d_ws, size_t ws_size,
                              hipStream_t stream)
{
    const float* pred_boxes = (const float*)d_in[0];  // [B,P,4]
    const float* scores     = (const float*)d_in[1];  // [B,P,C]
    const float* gt_boxes   = (const float*)d_in[2];  // [B,G,4]
    const int*   gt_labels  = (const int*)d_in[3];    // [B,G]
    const float* priors     = (const float*)d_in[4];  // [P,4]
    float* out = (float*)d_out;

    char* ws = (char*)d_ws;
    double* acc    = (double*)ws;                  // [0]=l1, [1]=pos, [2]=neg
    int*    totpos = (int*)(ws + 32);
    int*    done   = (int*)(ws + 40);
    float2* lse_s0 = (float2*)(ws + 4096);         // [B*P] 4.5 MB

    lse_kernel<<<NBP / 64, 256, 0, stream>>>(scores, lse_s0,
                                             (unsigned long long*)ws);
    match_mine_kernel<<<NB, MT, 0, stream>>>(gt_boxes, gt_labels, priors,
                                             pred_boxes, scores, lse_s0,
                                             acc, totpos, done, out);
}

// Round 2
// 316.169 us; speedup vs baseline: 1.0055x; 1.0044x over previous
//
#include <hip/hip_runtime.h>
#include <cstdint>
#include <math.h>

#define NB 64
#define NP 8732
#define NC 81
#define NG 16
#define THRESH 0.5f
#define NBP (NB * NP)
#define MT 512           // match_mine block size (8 waves)
#define NSW 18           // ceil(NP / MT)

// ---------------------------------------------------------------------------
// Kernel 1: log-sum-exp per row (independent of matching). Also zeroes the
// 64-byte accumulator block (block 0). UNCHANGED from R1 (control).
// ---------------------------------------------------------------------------
__global__ __launch_bounds__(256) void lse_kernel(
    const float* __restrict__ scores,   // [B*P, C]
    float2* __restrict__ lse_s0,        // [B*P] {lse, score0}
    unsigned long long* __restrict__ zero64)  // ws base: acc/total_pos/done
{
    if (blockIdx.x == 0 && threadIdx.x < 8)
        zero64[threadIdx.x] = 0ull;     // zeroes acc[0..2], total_pos, done

    __shared__ __align__(16) float tile[64 * NC];  // 20736 B
    const int t = threadIdx.x;
    const size_t row0 = (size_t)blockIdx.x * 64;
    const float* gbase = scores + row0 * NC;

    const float4* g4 = (const float4*)gbase;
    float4* l4 = (float4*)tile;
#pragma unroll
    for (int i = 0; i < 5; ++i)
        l4[i * 256 + t] = g4[i * 256 + t];
    if (t < 64) tile[5120 + t] = gbase[5120 + t];
    __syncthreads();

    const int r = t >> 2;
    const int c4 = t & 3;
    const float* rp = tile + r * NC;
    float s = 0.0f;
#pragma unroll
    for (int i = 0; i < 21; ++i) {
        const int j = c4 + 4 * i;
        if (j < NC) s += __expf(rp[j]);
    }
    s += __shfl_xor(s, 1, 64);
    s += __shfl_xor(s, 2, 64);

    if (c4 == 0)
        lse_s0[row0 + r] = make_float2(__logf(s), rp[0]);
}

// ---------------------------------------------------------------------------
// Kernel 2: fused match + CE assembly + hard-negative select.
// R2 changes (phase C only):
//  - pass-0 radix histogram is FUSED into phase B (ce value is in-register
//    there) -> one fewer full 8732-element LDS sweep.
//  - per-wave sub-histograms wh[8][256] (+8 KB LDS) -> 8x lower same-address
//    LDS-atomic contention; combined into hist[256] by 256 threads.
// ---------------------------------------------------------------------------
__global__ __launch_bounds__(MT) void match_mine_kernel(
    const float* __restrict__ gt_boxes,    // [B,G,4] corner form
    const int* __restrict__ gt_labels,     // [B,G]
    const float* __restrict__ priors,      // [P,4] center form
    const float* __restrict__ pred_boxes,  // [B,P,4]
    const float* __restrict__ scores,      // [B,P,C]
    const float2* __restrict__ lse_s0,     // [B*P]
    double* __restrict__ acc,              // [0]=l1, [1]=pos, [2]=neg
    int* __restrict__ total_pos,
    int* __restrict__ done,
    float* __restrict__ out)
{
    __shared__ float s_ce[NP];             // overlaps, then ce values
    __shared__ unsigned char s_idx[NP];    // best gt per prior
    __shared__ __align__(16) float s_gt[NG][4];
    __shared__ int   s_lab[NG];
    __shared__ float w_val[8][NG];
    __shared__ int   w_idx[8][NG];
    __shared__ int   s_bp[NG];
    __shared__ float w_l1[8], w_pos[8], w_ns[8];
    __shared__ int   w_np[8];
    __shared__ __align__(16) int wh[8][256];   // per-wave sub-histograms
    __shared__ __align__(16) int hist[256];
    __shared__ int   s_digit, s_rem, s_k;

    const int b = blockIdx.x;
    const int tid = threadIdx.x;
    const int lane = tid & 63;
    const int wid = tid >> 6;

    if (tid < NG * 4) ((float*)s_gt)[tid] = gt_boxes[b * NG * 4 + tid];
    if (tid >= 64 && tid < 64 + NG) s_lab[tid - 64] = gt_labels[b * NG + (tid - 64)];
    // zero the pass-0 sub-histograms early (covered by the next barrier;
    // nothing touches wh until phase B).
    ((int4*)wh)[tid] = make_int4(0, 0, 0, 0);   // 2048 ints / 4 = 512 int4
    __syncthreads();

    // Prefetch lse_s0 into registers; consumed in phase B (hidden under A).
    float2 ls[NSW];
#pragma unroll
    for (int i = 0; i < NSW; ++i) {
        const int p = tid + i * MT;
        ls[i] = (p < NP) ? lse_s0[(size_t)b * NP + p] : make_float2(0.0f, 0.0f);
    }

    // Hoist gt boxes + areas into registers.
    float4 rgt[NG];
    float  rga[NG];
#pragma unroll
    for (int g = 0; g < NG; ++g) {
        rgt[g] = ((const float4*)s_gt)[g];
        rga[g] = (rgt[g].z - rgt[g].x) * (rgt[g].w - rgt[g].y);
    }

    // ---- Phase A: IoU; per-prior argmax over gt; per-gt argmax over priors.
    float bp_val[NG];
    int   bp_pidx[NG];
#pragma unroll
    for (int g = 0; g < NG; ++g) { bp_val[g] = -1.0f; bp_pidx[g] = 0; }

    for (int p = tid; p < NP; p += MT) {
        const float4 pr = ((const float4*)priors)[p];
        const float px1 = pr.x - pr.z * 0.5f;
        const float py1 = pr.y - pr.w * 0.5f;
        const float px2 = pr.x + pr.z * 0.5f;
        const float py2 = pr.y + pr.w * 0.5f;
        const float ap = (px2 - px1) * (py2 - py1);
        float bt_ov = -1.0f;
        int   bt_idx = 0;
#pragma unroll
        for (int g = 0; g < NG; ++g) {
            const float ltx = fmaxf(rgt[g].x, px1);
            const float lty = fmaxf(rgt[g].y, py1);
            const float rbx = fminf(rgt[g].z, px2);
            const float rby = fminf(rgt[g].w, py2);
            const float wx = fmaxf(rbx - ltx, 0.0f);
            const float wy = fmaxf(rby - lty, 0.0f);
            const float inter = wx * wy;
            const float iou = __fdividef(inter, rga[g] + ap - inter);
            if (iou > bt_ov) { bt_ov = iou; bt_idx = g; }             // first max over g
            if (iou > bp_val[g]) { bp_val[g] = iou; bp_pidx[g] = p; } // first max over p
        }
        s_ce[p] = bt_ov;
        s_idx[p] = (unsigned char)bt_idx;
    }

    // Per-wave shuffle argmax (val desc, idx asc on ties) per gt.
#pragma unroll
    for (int g = 0; g < NG; ++g) {
        float v = bp_val[g];
        int   ix = bp_pidx[g];
#pragma unroll
        for (int off = 32; off > 0; off >>= 1) {
            const float v2 = __shfl_xor(v, off, 64);
            const int   i2 = __shfl_xor(ix, off, 64);
            if (v2 > v || (v2 == v && i2 < ix)) { v = v2; ix = i2; }
        }
        if (lane == 0) { w_val[wid][g] = v; w_idx[wid][g] = ix; }
    }
    __syncthreads();
    if (tid < NG) {
        float bv = w_val[0][tid];
        int   bi = w_idx[0][tid];
#pragma unroll
        for (int w = 1; w < 8; ++w) {
            const float v2 = w_val[w][tid];
            const int   i2 = w_idx[w][tid];
            if (v2 > bv || (v2 == bv && i2 < bi)) { bv = v2; bi = i2; }
        }
        s_bp[tid] = bi;
    }
    __syncthreads();
    if (tid == 0) {   // sequential override: later g wins on duplicate priors
        for (int g = 0; g < NG; ++g) {
            const int p = s_bp[g];
            s_ce[p] = 2.0f;
            s_idx[p] = (unsigned char)g;
        }
    }
    __syncthreads();

    // ---- Phase B: confidence targets, CE assembly, L1 on positives.
    //      Pass-0 radix histogram (top byte of key = ce*2048) fused in.
    int my_npos = 0;
    float my_l1 = 0.0f, my_pos = 0.0f;
#pragma unroll
    for (int i = 0; i < NSW; ++i) {
        const int p = tid + i * MT;
        if (p < NP) {
            const int g = s_idx[p];
            const float ov = s_ce[p];
            const int cf = (ov < THRESH) ? 0 : s_lab[g];
            float cev;
            if (cf != 0) {
                my_pos += ls[i].x - scores[((size_t)b * NP + p) * NC + cf];
                ++my_npos;
                cev = 0.0f;
                s_ce[p] = 0.0f;
                const float4 pr = ((const float4*)priors)[p];
                const float x1 = s_gt[g][0], y1 = s_gt[g][1];
                const float x2 = s_gt[g][2], y2 = s_gt[g][3];
                const float mcx = (x1 + x2) * 0.5f;
                const float mcy = (y1 + y2) * 0.5f;
                const float mw = x2 - x1, mh = y2 - y1;
                const float gx = (mcx - pr.x) / (0.1f * pr.z);
                const float gy = (mcy - pr.y) / (0.1f * pr.w);
                const float gw = logf(mw / pr.z) / 0.2f;
                const float gh = logf(mh / pr.w) / 0.2f;
                const float4 pb = ((const float4*)pred_boxes)[(size_t)b * NP + p];
                my_l1 += fabsf(pb.x - gx) + fabsf(pb.y - gy) +
                         fabsf(pb.z - gw) + fabsf(pb.w - gh);
            } else {
                cev = ls[i].x - ls[i].y;   // lse - score0 >= 0
                s_ce[p] = cev;
            }
            const unsigned int key = (unsigned int)(cev * 2048.0f);
            atomicAdd(&wh[wid][key >> 8], 1);
        }
    }

#pragma unroll
    for (int off = 32; off > 0; off >>= 1) {
        my_l1 += __shfl_xor(my_l1, off, 64);
        my_pos += __shfl_xor(my_pos, off, 64);
        my_npos += __shfl_xor(my_npos, off, 64);
    }
    if (lane == 0) { w_l1[wid] = my_l1; w_pos[wid] = my_pos; w_np[wid] = my_npos; }
    __syncthreads();
    if (tid == 0) {
        int np = 0;
#pragma unroll
        for (int w = 0; w < 8; ++w) np += w_np[w];
        s_k = np;
    }
    if (tid < 256) {     // combine pass-0 sub-histograms
        int s = 0;
#pragma unroll
        for (int w = 0; w < 8; ++w) s += wh[w][tid];
        hist[tid] = s;
    }
    __syncthreads();

    // ---- Phase C: top-k sum via 2-level radix select on key = ce * 2048.
    //      Pass-0 histogram already built; only ONE more full sweep for
    //      pass 1, then the threshold-sum sweep.
    int k = 3 * s_k;
    if (k > NP) k = NP;
    double neg_total = 0.0;
    if (k > 0) {   // block-uniform branch
        int rem = k;

        // --- digit pick on hist (pass 0): single-wave shfl suffix-scan.
        if (wid == 0) {
            const int4 h = ((const int4*)hist)[lane];  // bins 4*lane..4*lane+3
            const int local = h.x + h.y + h.z + h.w;
            int suf = local;
#pragma unroll
            for (int off = 1; off < 64; off <<= 1) {
                const int o = __shfl_down(suf, off, 64);
                if (lane + off < 64) suf += o;
            }
            const int above = suf - local;   // count in lanes > lane
            const int ge3 = above + h.w;     // count with digit >= 4l+3
            const int ge2 = ge3 + h.z;
            const int ge1 = ge2 + h.y;
            const int ge0 = ge1 + h.x;
            const unsigned long long mask = __ballot(ge0 >= rem);
            if (mask == 0) {
                if (lane == 0) { s_digit = 0; s_rem = rem; }
            } else {
                const int lstar = 63 - __clzll(mask);
                if (lane == lstar) {
                    int d, greater;
                    if (ge3 >= rem)      { d = 4 * lane + 3; greater = above; }
                    else if (ge2 >= rem) { d = 4 * lane + 2; greater = ge3; }
                    else if (ge1 >= rem) { d = 4 * lane + 1; greater = ge2; }
                    else                 { d = 4 * lane + 0; greater = ge1; }
                    s_digit = d;
                    s_rem = rem - greater;
                }
            }
        }
        __syncthreads();
        const unsigned int d1 = (unsigned int)s_digit;
        rem = s_rem;

        // --- pass 1: zero sub-hists, sweep s_ce conditioned on top byte.
        ((int4*)wh)[tid] = make_int4(0, 0, 0, 0);
        __syncthreads();
        for (int p = tid; p < NP; p += MT) {
            const unsigned int key = (unsigned int)(s_ce[p] * 2048.0f);
            if ((key >> 8) == d1)
                atomicAdd(&wh[wid][key & 255u], 1);
        }
        __syncthreads();
        if (tid < 256) {
            int s = 0;
#pragma unroll
            for (int w = 0; w < 8; ++w) s += wh[w][tid];
            hist[tid] = s;
        }
        __syncthreads();

        // --- digit pick on hist (pass 1).
        if (wid == 0) {
            const int4 h = ((const int4*)hist)[lane];
            const int local = h.x + h.y + h.z + h.w;
            int suf = local;
#pragma unroll
            for (int off = 1; off < 64; off <<= 1) {
                const int o = __shfl_down(suf, off, 64);
                if (lane + off < 64) suf += o;
            }
            const int above = suf - local;
            const int ge3 = above + h.w;
            const int ge2 = ge3 + h.z;
            const int ge1 = ge2 + h.y;
            const int ge0 = ge1 + h.x;
            const unsigned long long mask = __ballot(ge0 >= rem);
            if (mask == 0) {
                if (lane == 0) { s_digit = 0; s_rem = rem; }
            } else {
                const int lstar = 63 - __clzll(mask);
                if (lane == lstar) {
                    int d, greater;
                    if (ge3 >= rem)      { d = 4 * lane + 3; greater = above; }
                    else if (ge2 >= rem) { d = 4 * lane + 2; greater = ge3; }
                    else if (ge1 >= rem) { d = 4 * lane + 1; greater = ge2; }
                    else                 { d = 4 * lane + 0; greater = ge1; }
                    s_digit = d;
                    s_rem = rem - greater;
                }
            }
        }
        __syncthreads();
        rem = s_rem;

        const unsigned int T = (d1 << 8) | (unsigned int)s_digit;
        float local = 0.0f;
        for (int p = tid; p < NP; p += MT) {
            const float x = s_ce[p];
            if ((unsigned int)(x * 2048.0f) > T) local += x;
        }
#pragma unroll
        for (int off = 32; off > 0; off >>= 1)
            local += __shfl_xor(local, off, 64);
        if (lane == 0) w_ns[wid] = local;
        __syncthreads();
        if (tid == 0) {
            float ns = 0.0f;
#pragma unroll
            for (int w = 0; w < 8; ++w) ns += w_ns[w];
            neg_total = (double)ns +
                        (double)rem * (((double)T + 0.5) * (1.0 / 2048.0));
        }
    }

    if (tid == 0) {
        float l1 = 0.0f, ps = 0.0f;
#pragma unroll
        for (int w = 0; w < 8; ++w) { l1 += w_l1[w]; ps += w_pos[w]; }
        atomicAdd(&acc[0], (double)l1);
        atomicAdd(&acc[1], (double)ps);
        atomicAdd(&acc[2], neg_total);
        atomicAdd(total_pos, s_k);
        __threadfence();
        if (atomicAdd(done, 1) == NB - 1) {
            __threadfence();
            const double tp  = (double)atomicAdd(total_pos, 0);
            const double dl1 = atomicAdd(&acc[0], 0.0);
            const double dps = atomicAdd(&acc[1], 0.0);
            const double dng = atomicAdd(&acc[2], 0.0);
            out[0] = (float)((dng + dps) / tp);   // confidence loss
            out[1] = (float)(dl1 / (tp * 4.0));   // ALPHA * location loss
        }
    }
}

// ---------------------------------------------------------------------------
extern "C" void kernel_launch(void* const* d_in, const int* in_sizes, int n_in,
                              void* d_out, int out_size, void* d_ws, size_t ws_size,
                              hipStream_t stream)
{
    const float* pred_boxes = (const float*)d_in[0];  // [B,P,4]
    const float* scores     = (const float*)d_in[1];  // [B,P,C]
    const float* gt_boxes   = (const float*)d_in[2];  // [B,G,4]
    const int*   gt_labels  = (const int*)d_in[3];    // [B,G]
    const float* priors     = (const float*)d_in[4];  // [P,4]
    float* out = (float*)d_out;

    char* ws = (char*)d_ws;
    double* acc    = (double*)ws;                  // [0]=l1, [1]=pos, [2]=neg
    int*    totpos = (int*)(ws + 32);
    int*    done   = (int*)(ws + 40);
    float2* lse_s0 = (float2*)(ws + 4096);         // [B*P] 4.5 MB

    lse_kernel<<<NBP / 64, 256, 0, stream>>>(scores, lse_s0,
                                             (unsigned long long*)ws);
    match_mine_kernel<<<NB, MT, 0, stream>>>(gt_boxes, gt_labels, priors,
                                             pred_boxes, scores, lse_s0,
                                             acc, totpos, done, out);
}